// Round 1
// baseline (1080.323 us; speedup 1.0000x reference)
//
#include <hip/hip_runtime.h>
#include <cstdint>

#define EDIM 1024
#define NHEADS 16
#define HDIM 64
#define BATCH 2
#define SEQ 2048
#define MROWS (BATCH * SEQ) // 4096

// ---------------------------------------------------------------------------
// GEMM NT: C[M,N] = A[M,K] @ W[N,K]^T + bias[N]   (fp32, 128x128x32 tiles)
// MODE 0: scatter C into Q/K/V buffers laid out [B,H,S,D], N=3072
// MODE 1: C += residual, write y[M,N], N=1024
// ---------------------------------------------------------------------------
template <int MODE>
__global__ __launch_bounds__(256, 2) void gemm_nt_kernel(
    const float* __restrict__ A, const float* __restrict__ W,
    const float* __restrict__ bias, const float* __restrict__ resid,
    float* __restrict__ out0, float* __restrict__ out1,
    float* __restrict__ out2, int M, int N, int K) {
  __shared__ float As[32][132]; // [k][m], pad 4 -> 16B-aligned rows
  __shared__ float Bs[32][132]; // [k][n]
  const int tid = threadIdx.x;
  const int tx = tid & 15, ty = tid >> 4;
  const int row0 = blockIdx.y * 128;
  const int col0 = blockIdx.x * 128;

  float acc[8][8];
#pragma unroll
  for (int i = 0; i < 8; ++i)
#pragma unroll
    for (int j = 0; j < 8; ++j) acc[i][j] = 0.f;

  for (int k0 = 0; k0 < K; k0 += 32) {
    __syncthreads();
#pragma unroll
    for (int t = 0; t < 4; ++t) {
      const int flat = t * 256 + tid;
      const int r = flat >> 3, kc = flat & 7;
      const float4 va = *reinterpret_cast<const float4*>(
          &A[(size_t)(row0 + r) * K + k0 + kc * 4]);
      As[kc * 4 + 0][r] = va.x;
      As[kc * 4 + 1][r] = va.y;
      As[kc * 4 + 2][r] = va.z;
      As[kc * 4 + 3][r] = va.w;
      const float4 vb = *reinterpret_cast<const float4*>(
          &W[(size_t)(col0 + r) * K + k0 + kc * 4]);
      Bs[kc * 4 + 0][r] = vb.x;
      Bs[kc * 4 + 1][r] = vb.y;
      Bs[kc * 4 + 2][r] = vb.z;
      Bs[kc * 4 + 3][r] = vb.w;
    }
    __syncthreads();
#pragma unroll
    for (int kk = 0; kk < 32; ++kk) {
      float a[8], b[8];
      *reinterpret_cast<float4*>(&a[0]) =
          *reinterpret_cast<const float4*>(&As[kk][ty * 8]);
      *reinterpret_cast<float4*>(&a[4]) =
          *reinterpret_cast<const float4*>(&As[kk][ty * 8 + 4]);
      *reinterpret_cast<float4*>(&b[0]) =
          *reinterpret_cast<const float4*>(&Bs[kk][tx * 8]);
      *reinterpret_cast<float4*>(&b[4]) =
          *reinterpret_cast<const float4*>(&Bs[kk][tx * 8 + 4]);
#pragma unroll
      for (int i = 0; i < 8; ++i)
#pragma unroll
        for (int j = 0; j < 8; ++j) acc[i][j] = fmaf(a[i], b[j], acc[i][j]);
    }
  }

#pragma unroll
  for (int i = 0; i < 8; ++i) {
    const int m = row0 + ty * 8 + i;
#pragma unroll
    for (int jg = 0; jg < 2; ++jg) {
      const int n0 = col0 + tx * 8 + jg * 4;
      const float4 bb = *reinterpret_cast<const float4*>(&bias[n0]);
      float4 v;
      v.x = acc[i][jg * 4 + 0] + bb.x;
      v.y = acc[i][jg * 4 + 1] + bb.y;
      v.z = acc[i][jg * 4 + 2] + bb.z;
      v.w = acc[i][jg * 4 + 3] + bb.w;
      if (MODE == 0) {
        // n0 -> (which, h, d); m -> (b, s). which/h uniform per block (128|1024)
        const int which = n0 >> 10;
        const int rem = n0 & 1023;
        const int h = rem >> 6, d = rem & 63;
        const int b = m >> 11, s = m & 2047;
        float* dst = (which == 0) ? out0 : ((which == 1) ? out1 : out2);
        *reinterpret_cast<float4*>(
            &dst[((size_t)(b * NHEADS + h) * SEQ + s) * HDIM + d]) = v;
      } else {
        const float4 rr =
            *reinterpret_cast<const float4*>(&resid[(size_t)m * N + n0]);
        v.x += rr.x;
        v.y += rr.y;
        v.z += rr.z;
        v.w += rr.w;
        *reinterpret_cast<float4*>(&out0[(size_t)m * N + n0]) = v;
      }
    }
  }
}

// ---------------------------------------------------------------------------
// Flash attention fp32: per (b,h) head, 64-row Q tiles, 64-row K/V tiles.
// Q pre-scaled by 1/sqrt(D). Online softmax (running m,l per row).
// LDS: Q^T[d][i], K^T[d][j] (buffer reused for P^T[j][i]), V[j][d].
// Thread (tx,ty): rows i=ty*4..+3, cols j/d = tx*4..+3. Row reduce over tx
// lanes via shfl_xor (tid bits 0..3).
// ---------------------------------------------------------------------------
__global__ __launch_bounds__(256, 2) void attn_kernel(
    const float* __restrict__ Qb, const float* __restrict__ Kb,
    const float* __restrict__ Vb, float* __restrict__ AO) {
  __shared__ float Qt[64][68];
  __shared__ float KPt[64][68]; // K^T during QK, then P^T during PV
  __shared__ float Vs[64][68];
  const int tid = threadIdx.x;
  const int tx = tid & 15, ty = tid >> 4;
  const int qt = blockIdx.x; // 0..31
  const int bh = blockIdx.y; // 0..31 == b*NHEADS+h
  const size_t base = (size_t)bh * SEQ * HDIM;

#pragma unroll
  for (int t = 0; t < 4; ++t) {
    const int flat = t * 256 + tid;
    const int r = flat >> 4, dc = flat & 15;
    const float4 v = *reinterpret_cast<const float4*>(
        &Qb[base + (size_t)(qt * 64 + r) * HDIM + dc * 4]);
    Qt[dc * 4 + 0][r] = v.x * 0.125f;
    Qt[dc * 4 + 1][r] = v.y * 0.125f;
    Qt[dc * 4 + 2][r] = v.z * 0.125f;
    Qt[dc * 4 + 3][r] = v.w * 0.125f;
  }

  float o[4][4];
#pragma unroll
  for (int r = 0; r < 4; ++r)
#pragma unroll
    for (int c = 0; c < 4; ++c) o[r][c] = 0.f;
  float m_i[4] = {-1e30f, -1e30f, -1e30f, -1e30f};
  float l_i[4] = {0.f, 0.f, 0.f, 0.f};

  for (int kt = 0; kt < 32; ++kt) {
    __syncthreads(); // prior PV reads of KPt/Vs complete
#pragma unroll
    for (int t = 0; t < 4; ++t) {
      const int flat = t * 256 + tid;
      const int r = flat >> 4, dc = flat & 15;
      const float4 v = *reinterpret_cast<const float4*>(
          &Kb[base + (size_t)(kt * 64 + r) * HDIM + dc * 4]);
      KPt[dc * 4 + 0][r] = v.x;
      KPt[dc * 4 + 1][r] = v.y;
      KPt[dc * 4 + 2][r] = v.z;
      KPt[dc * 4 + 3][r] = v.w;
      const float4 w = *reinterpret_cast<const float4*>(
          &Vb[base + (size_t)(kt * 64 + r) * HDIM + dc * 4]);
      *reinterpret_cast<float4*>(&Vs[r][dc * 4]) = w;
    }
    __syncthreads();

    float sacc[4][4];
#pragma unroll
    for (int r = 0; r < 4; ++r)
#pragma unroll
      for (int c = 0; c < 4; ++c) sacc[r][c] = 0.f;
#pragma unroll
    for (int d = 0; d < 64; ++d) {
      float a[4], b[4];
      *reinterpret_cast<float4*>(a) =
          *reinterpret_cast<const float4*>(&Qt[d][ty * 4]);
      *reinterpret_cast<float4*>(b) =
          *reinterpret_cast<const float4*>(&KPt[d][tx * 4]);
#pragma unroll
      for (int r = 0; r < 4; ++r)
#pragma unroll
        for (int c = 0; c < 4; ++c) sacc[r][c] = fmaf(a[r], b[c], sacc[r][c]);
    }

    // online softmax per row (rows replicated across the 16 tx lanes)
    float alpha[4];
#pragma unroll
    for (int r = 0; r < 4; ++r) {
      float rm = fmaxf(fmaxf(sacc[r][0], sacc[r][1]),
                       fmaxf(sacc[r][2], sacc[r][3]));
#pragma unroll
      for (int off = 1; off < 16; off <<= 1) rm = fmaxf(rm, __shfl_xor(rm, off));
      const float mn = fmaxf(m_i[r], rm);
      alpha[r] = __expf(m_i[r] - mn);
      m_i[r] = mn;
      float rs = 0.f;
#pragma unroll
      for (int c = 0; c < 4; ++c) {
        const float p = __expf(sacc[r][c] - mn);
        sacc[r][c] = p;
        rs += p;
      }
#pragma unroll
      for (int off = 1; off < 16; off <<= 1) rs += __shfl_xor(rs, off);
      l_i[r] = l_i[r] * alpha[r] + rs;
#pragma unroll
      for (int c = 0; c < 4; ++c) o[r][c] *= alpha[r];
    }

    __syncthreads(); // all QK reads of KPt done -> safe to overwrite with P^T
#pragma unroll
    for (int r = 0; r < 4; ++r)
#pragma unroll
      for (int c = 0; c < 4; ++c) KPt[tx * 4 + c][ty * 4 + r] = sacc[r][c];
    __syncthreads(); // P^T visible

#pragma unroll
    for (int j = 0; j < 64; ++j) {
      float pa[4], vv[4];
      *reinterpret_cast<float4*>(pa) =
          *reinterpret_cast<const float4*>(&KPt[j][ty * 4]);
      *reinterpret_cast<float4*>(vv) =
          *reinterpret_cast<const float4*>(&Vs[j][tx * 4]);
#pragma unroll
      for (int r = 0; r < 4; ++r)
#pragma unroll
        for (int c = 0; c < 4; ++c) o[r][c] = fmaf(pa[r], vv[c], o[r][c]);
    }
  }

  const int b = bh >> 4, h = bh & 15;
#pragma unroll
  for (int r = 0; r < 4; ++r) {
    const float inv = 1.f / l_i[r];
    float4 v;
    v.x = o[r][0] * inv;
    v.y = o[r][1] * inv;
    v.z = o[r][2] * inv;
    v.w = o[r][3] * inv;
    const int s = qt * 64 + ty * 4 + r;
    *reinterpret_cast<float4*>(
        &AO[((size_t)(b * SEQ + s)) * EDIM + h * HDIM + tx * 4]) = v;
  }
}

// ---------------------------------------------------------------------------
// In-place LayerNorm over last dim (E=1024). One block per row, 256 threads,
// float4 per thread. eps = 1e-5.
// ---------------------------------------------------------------------------
__global__ __launch_bounds__(256) void ln_kernel(float* __restrict__ y,
                                                 const float* __restrict__ gamma,
                                                 const float* __restrict__ beta) {
  const int row = blockIdx.x, tid = threadIdx.x;
  const float4 v =
      *reinterpret_cast<const float4*>(&y[(size_t)row * EDIM + tid * 4]);
  float s = v.x + v.y + v.z + v.w;
  float s2 = v.x * v.x + v.y * v.y + v.z * v.z + v.w * v.w;
#pragma unroll
  for (int off = 1; off < 64; off <<= 1) {
    s += __shfl_xor(s, off);
    s2 += __shfl_xor(s2, off);
  }
  __shared__ float red[8];
  if ((tid & 63) == 0) {
    red[(tid >> 6) * 2 + 0] = s;
    red[(tid >> 6) * 2 + 1] = s2;
  }
  __syncthreads();
  s = red[0] + red[2] + red[4] + red[6];
  s2 = red[1] + red[3] + red[5] + red[7];
  const float mean = s * (1.f / 1024.f);
  const float var = fmaxf(s2 * (1.f / 1024.f) - mean * mean, 0.f);
  const float rstd = rsqrtf(var + 1e-5f);
  const float4 g = *reinterpret_cast<const float4*>(&gamma[tid * 4]);
  const float4 be = *reinterpret_cast<const float4*>(&beta[tid * 4]);
  float4 outv;
  outv.x = (v.x - mean) * rstd * g.x + be.x;
  outv.y = (v.y - mean) * rstd * g.y + be.y;
  outv.z = (v.z - mean) * rstd * g.z + be.z;
  outv.w = (v.w - mean) * rstd * g.w + be.w;
  *reinterpret_cast<float4*>(&y[(size_t)row * EDIM + tid * 4]) = outv;
}

extern "C" void kernel_launch(void* const* d_in, const int* in_sizes, int n_in,
                              void* d_out, int out_size, void* d_ws,
                              size_t ws_size, hipStream_t stream) {
  const float* x = (const float*)d_in[0];
  const float* W_qkv = (const float*)d_in[1];
  const float* b_qkv = (const float*)d_in[2];
  const float* W_proj = (const float*)d_in[3];
  const float* b_proj = (const float*)d_in[4];
  const float* gamma = (const float*)d_in[5];
  const float* beta = (const float*)d_in[6];
  float* out = (float*)d_out;
  float* ws = (float*)d_ws;

  const size_t PLANE = (size_t)MROWS * EDIM; // 4M floats = 16 MB
  float* Qb = ws;             // [B,H,S,D]
  float* Kb = ws + PLANE;     // [B,H,S,D]
  float* Vb = ws + 2 * PLANE; // [B,H,S,D]
  float* AO = ws + 3 * PLANE; // [B,S,E]

  // 1) QKV projection + scatter to [B,H,S,D]
  gemm_nt_kernel<0><<<dim3(24, 32), 256, 0, stream>>>(
      x, W_qkv, b_qkv, nullptr, Qb, Kb, Vb, MROWS, 3 * EDIM, EDIM);
  // 2) flash attention -> AO [B,S,E]
  attn_kernel<<<dim3(32, 32), 256, 0, stream>>>(Qb, Kb, Vb, AO);
  // 3) output projection + bias + residual -> d_out (pre-LN y)
  gemm_nt_kernel<1><<<dim3(8, 32), 256, 0, stream>>>(
      AO, W_proj, b_proj, x, out, nullptr, nullptr, MROWS, EDIM, EDIM);
  // 4) in-place LayerNorm
  ln_kernel<<<MROWS, 256, 0, stream>>>(out, gamma, beta);
}

// Round 3
// 322.191 us; speedup vs baseline: 3.3530x; 3.3530x over previous
//
#include <hip/hip_runtime.h>
#include <cstdint>

#define EDIM 1024
#define NHEADS 16
#define HDIM 64
#define BATCH 2
#define SEQ 2048
#define MROWS (BATCH * SEQ) // 4096

typedef __attribute__((ext_vector_type(8))) short bf16x8; // 8 bf16 = 4 VGPR
typedef __attribute__((ext_vector_type(4))) float f32x4;

__device__ __forceinline__ unsigned short f2bf(float f) {
  union { float f; unsigned u; } v; v.f = f;
  unsigned r = v.u + 0x7FFFu + ((v.u >> 16) & 1u); // RNE
  return (unsigned short)(r >> 16);
}

// ---------------------------------------------------------------------------
// fp32 -> bf16 bulk convert (n multiple of 8)
// ---------------------------------------------------------------------------
__global__ __launch_bounds__(256) void cvt_kernel(const float* __restrict__ in,
                                                  unsigned short* __restrict__ out,
                                                  int n) {
  const int i = (blockIdx.x * 256 + threadIdx.x) * 8;
  if (i >= n) return;
  const float4 a = *(const float4*)&in[i];
  const float4 b = *(const float4*)&in[i + 4];
  unsigned short u[8];
  u[0] = f2bf(a.x); u[1] = f2bf(a.y); u[2] = f2bf(a.z); u[3] = f2bf(a.w);
  u[4] = f2bf(b.x); u[5] = f2bf(b.y); u[6] = f2bf(b.z); u[7] = f2bf(b.w);
  *(uint4*)&out[i] = *(uint4*)u;
}

// ---------------------------------------------------------------------------
// bf16 MFMA GEMM NT: C[M,N] = A[M,K] @ W[N,K]^T + bias   (128x128 tile, BK=64)
// 4 waves (2x2), each 64x64 = 4x4 frags of 16x16x32.
// MODE 0: scatter to Q(*0.125)/K/V bf16 [B,H,S,D].  MODE 1: +resid, fp32 out.
// ---------------------------------------------------------------------------
template <int MODE>
__global__ __launch_bounds__(256) void gemm_bf16(
    const unsigned short* __restrict__ A, const unsigned short* __restrict__ Bw,
    const float* __restrict__ bias, const float* __restrict__ resid,
    unsigned short* __restrict__ q_out, unsigned short* __restrict__ k_out,
    unsigned short* __restrict__ v_out, float* __restrict__ y_out,
    int M, int N, int K) {
  __shared__ unsigned short As[128 * 72]; // [row][k], pad 64->72 (bank spread)
  __shared__ unsigned short Bs[128 * 72];
  const int tid = threadIdx.x;
  const int lane = tid & 63, w = tid >> 6;
  const int wr = w >> 1, wc = w & 1;
  const int l15 = lane & 15, g = lane >> 4;
  const int row0 = blockIdx.y * 128, col0 = blockIdx.x * 128;

  f32x4 acc[4][4];
#pragma unroll
  for (int i = 0; i < 4; ++i)
#pragma unroll
    for (int j = 0; j < 4; ++j) acc[i][j] = (f32x4){0.f, 0.f, 0.f, 0.f};

  for (int k0 = 0; k0 < K; k0 += 64) {
    __syncthreads();
#pragma unroll
    for (int t = 0; t < 4; ++t) {
      const int chunk = t * 256 + tid; // 1024 chunks of 16B per array
      const int r = chunk >> 3, c8 = chunk & 7;
      const uint4 va = *(const uint4*)&A[(size_t)(row0 + r) * K + k0 + c8 * 8];
      *(uint4*)&As[r * 72 + c8 * 8] = va;
      const uint4 vb = *(const uint4*)&Bw[(size_t)(col0 + r) * K + k0 + c8 * 8];
      *(uint4*)&Bs[r * 72 + c8 * 8] = vb;
    }
    __syncthreads();
#pragma unroll
    for (int ks = 0; ks < 2; ++ks) {
      bf16x8 af[4], bfr[4];
#pragma unroll
      for (int i = 0; i < 4; ++i)
        af[i] = *(const bf16x8*)&As[(wr * 64 + i * 16 + l15) * 72 + ks * 32 + g * 8];
#pragma unroll
      for (int j = 0; j < 4; ++j)
        bfr[j] = *(const bf16x8*)&Bs[(wc * 64 + j * 16 + l15) * 72 + ks * 32 + g * 8];
#pragma unroll
      for (int i = 0; i < 4; ++i)
#pragma unroll
        for (int j = 0; j < 4; ++j)
          acc[i][j] = __builtin_amdgcn_mfma_f32_16x16x32_bf16(af[i], bfr[j],
                                                              acc[i][j], 0, 0, 0);
    }
  }

#pragma unroll
  for (int j = 0; j < 4; ++j) {
    const int nbase = col0 + wc * 64 + j * 16 + l15;
    const float bb = bias[nbase];
#pragma unroll
    for (int i = 0; i < 4; ++i) {
#pragma unroll
      for (int r = 0; r < 4; ++r) {
        const int m = row0 + wr * 64 + i * 16 + g * 4 + r;
        float v = acc[i][j][r] + bb;
        if (MODE == 0) {
          const int which = nbase >> 10;
          const int h = (nbase >> 6) & 15, d = nbase & 63;
          const int b = m >> 11, s = m & 2047;
          const size_t idx = ((size_t)(b * NHEADS + h) * SEQ + s) * HDIM + d;
          if (which == 0) q_out[idx] = f2bf(v * 0.125f); // fold 1/sqrt(D)
          else if (which == 1) k_out[idx] = f2bf(v);
          else v_out[idx] = f2bf(v);
        } else {
          v += resid[(size_t)m * N + nbase];
          y_out[(size_t)m * N + nbase] = v;
        }
      }
    }
  }
}

// ---------------------------------------------------------------------------
// V [B,H,S,D] -> Vt [B,H,D,S] tile transpose (64 s-rows per block)
// ---------------------------------------------------------------------------
__global__ __launch_bounds__(256) void vtrans_kernel(
    const unsigned short* __restrict__ V, unsigned short* __restrict__ Vt) {
  __shared__ unsigned short T[64 * 72];
  const int tid = threadIdx.x;
  const int st = blockIdx.x, bh = blockIdx.y;
  const size_t ibase = (size_t)bh * SEQ * HDIM + (size_t)st * 64 * HDIM;
#pragma unroll
  for (int t = 0; t < 2; ++t) {
    const int chunk = t * 256 + tid; // 512 chunks of 16B
    const int r = chunk >> 3, c8 = chunk & 7;
    const uint4 v = *(const uint4*)&V[ibase + r * 64 + c8 * 8];
    *(uint4*)&T[r * 72 + c8 * 8] = v;
  }
  __syncthreads();
  const size_t obase = (size_t)bh * HDIM * SEQ + st * 64;
#pragma unroll
  for (int t = 0; t < 2; ++t) {
    const int chunk = t * 256 + tid;
    const int d = chunk >> 3, s8 = (chunk & 7) * 8;
    unsigned short u[8];
#pragma unroll
    for (int e = 0; e < 8; ++e) u[e] = T[(s8 + e) * 72 + d];
    *(uint4*)&Vt[obase + (size_t)d * SEQ + s8] = *(uint4*)u;
  }
}

// ---------------------------------------------------------------------------
// Flash attention, bf16 MFMA. Block = 4 waves, 128 q-rows (32/wave), KV tile 64.
// Q in regs (pre-scaled); K,V^T frags straight from global (L2-resident);
// P staged through wave-private LDS (no barriers in the k-loop).
// ---------------------------------------------------------------------------
__global__ __launch_bounds__(256) void attn_mfma(
    const unsigned short* __restrict__ Qb, const unsigned short* __restrict__ Kb,
    const unsigned short* __restrict__ Vt, unsigned short* __restrict__ AO) {
  __shared__ unsigned short P_lds[128 * 72]; // [q_local][key] bf16
  const int tid = threadIdx.x;
  const int lane = tid & 63, w = tid >> 6;
  const int l15 = lane & 15, g = lane >> 4;
  const int qt = blockIdx.x; // 16
  const int bh = blockIdx.y; // 32
  const int b = bh >> 4, h = bh & 15;
  const size_t hbase = (size_t)bh * SEQ * HDIM;
  const size_t vbase = (size_t)bh * HDIM * SEQ;
  const int q0 = qt * 128 + w * 32;

  bf16x8 aq[2][2];
#pragma unroll
  for (int i = 0; i < 2; ++i)
#pragma unroll
    for (int ks = 0; ks < 2; ++ks)
      aq[i][ks] = *(const bf16x8*)&Qb[hbase + (size_t)(q0 + i * 16 + l15) * HDIM +
                                      ks * 32 + g * 8];

  f32x4 o[2][4];
  float mi[2][4], li[2][4];
#pragma unroll
  for (int i = 0; i < 2; ++i)
#pragma unroll
    for (int jd = 0; jd < 4; ++jd) o[i][jd] = (f32x4){0.f, 0.f, 0.f, 0.f};
#pragma unroll
  for (int i = 0; i < 2; ++i)
#pragma unroll
    for (int r = 0; r < 4; ++r) { mi[i][r] = -1e30f; li[i][r] = 0.f; }

  for (int kt = 0; kt < SEQ / 64; ++kt) {
    f32x4 sc[2][4];
#pragma unroll
    for (int i = 0; i < 2; ++i)
#pragma unroll
      for (int j = 0; j < 4; ++j) sc[i][j] = (f32x4){0.f, 0.f, 0.f, 0.f};
#pragma unroll
    for (int ks = 0; ks < 2; ++ks) {
      bf16x8 bk[4];
#pragma unroll
      for (int j = 0; j < 4; ++j)
        bk[j] = *(const bf16x8*)&Kb[hbase + (size_t)(kt * 64 + j * 16 + l15) * HDIM +
                                    ks * 32 + g * 8];
#pragma unroll
      for (int i = 0; i < 2; ++i)
#pragma unroll
        for (int j = 0; j < 4; ++j)
          sc[i][j] = __builtin_amdgcn_mfma_f32_16x16x32_bf16(aq[i][ks], bk[j],
                                                             sc[i][j], 0, 0, 0);
    }
    // online softmax; rows live at (i, g, r), cols at (j, l15)
    float alpha[2][4];
#pragma unroll
    for (int i = 0; i < 2; ++i) {
#pragma unroll
      for (int r = 0; r < 4; ++r) {
        float tm = fmaxf(fmaxf(sc[i][0][r], sc[i][1][r]),
                         fmaxf(sc[i][2][r], sc[i][3][r]));
        tm = fmaxf(tm, __shfl_xor(tm, 1));
        tm = fmaxf(tm, __shfl_xor(tm, 2));
        tm = fmaxf(tm, __shfl_xor(tm, 4));
        tm = fmaxf(tm, __shfl_xor(tm, 8));
        const float mn = fmaxf(mi[i][r], tm);
        const float al = __expf(mi[i][r] - mn);
        mi[i][r] = mn;
        float rs = 0.f;
        unsigned short pb[4];
#pragma unroll
        for (int j = 0; j < 4; ++j) {
          const float p = __expf(sc[i][j][r] - mn);
          rs += p;
          pb[j] = f2bf(p);
        }
        rs += __shfl_xor(rs, 1);
        rs += __shfl_xor(rs, 2);
        rs += __shfl_xor(rs, 4);
        rs += __shfl_xor(rs, 8);
        li[i][r] = li[i][r] * al + rs;
        alpha[i][r] = al;
        const int prow = w * 32 + i * 16 + g * 4 + r;
#pragma unroll
        for (int j = 0; j < 4; ++j) P_lds[prow * 72 + j * 16 + l15] = pb[j];
      }
    }
#pragma unroll
    for (int i = 0; i < 2; ++i)
#pragma unroll
      for (int jd = 0; jd < 4; ++jd)
#pragma unroll
        for (int r = 0; r < 4; ++r) o[i][jd][r] *= alpha[i][r];
    // PV: A = P (wave-private LDS), B = V^T frags from global
#pragma unroll
    for (int ks = 0; ks < 2; ++ks) {
      bf16x8 ap[2], bv[4];
#pragma unroll
      for (int i = 0; i < 2; ++i)
        ap[i] = *(const bf16x8*)&P_lds[(w * 32 + i * 16 + l15) * 72 + ks * 32 + g * 8];
#pragma unroll
      for (int jd = 0; jd < 4; ++jd)
        bv[jd] = *(const bf16x8*)&Vt[vbase + (size_t)(jd * 16 + l15) * SEQ +
                                     kt * 64 + ks * 32 + g * 8];
#pragma unroll
      for (int i = 0; i < 2; ++i)
#pragma unroll
        for (int jd = 0; jd < 4; ++jd)
          o[i][jd] = __builtin_amdgcn_mfma_f32_16x16x32_bf16(ap[i], bv[jd],
                                                             o[i][jd], 0, 0, 0);
    }
  }

#pragma unroll
  for (int i = 0; i < 2; ++i) {
#pragma unroll
    for (int r = 0; r < 4; ++r) {
      const float inv = 1.f / li[i][r];
      const int s = qt * 128 + w * 32 + i * 16 + g * 4 + r;
#pragma unroll
      for (int jd = 0; jd < 4; ++jd)
        AO[(size_t)(b * SEQ + s) * EDIM + h * HDIM + jd * 16 + l15] =
            f2bf(o[i][jd][r] * inv);
    }
  }
}

// ---------------------------------------------------------------------------
// In-place LayerNorm over E=1024, eps=1e-5
// ---------------------------------------------------------------------------
__global__ __launch_bounds__(256) void ln_kernel(float* __restrict__ y,
                                                 const float* __restrict__ gamma,
                                                 const float* __restrict__ beta) {
  const int row = blockIdx.x, tid = threadIdx.x;
  const float4 v = *reinterpret_cast<const float4*>(&y[(size_t)row * EDIM + tid * 4]);
  float s = v.x + v.y + v.z + v.w;
  float s2 = v.x * v.x + v.y * v.y + v.z * v.z + v.w * v.w;
#pragma unroll
  for (int off = 1; off < 64; off <<= 1) {
    s += __shfl_xor(s, off);
    s2 += __shfl_xor(s2, off);
  }
  __shared__ float red[8];
  if ((tid & 63) == 0) {
    red[(tid >> 6) * 2 + 0] = s;
    red[(tid >> 6) * 2 + 1] = s2;
  }
  __syncthreads();
  s = red[0] + red[2] + red[4] + red[6];
  s2 = red[1] + red[3] + red[5] + red[7];
  const float mean = s * (1.f / 1024.f);
  const float var = fmaxf(s2 * (1.f / 1024.f) - mean * mean, 0.f);
  const float rstd = rsqrtf(var + 1e-5f);
  const float4 gm = *reinterpret_cast<const float4*>(&gamma[tid * 4]);
  const float4 be = *reinterpret_cast<const float4*>(&beta[tid * 4]);
  float4 outv;
  outv.x = (v.x - mean) * rstd * gm.x + be.x;
  outv.y = (v.y - mean) * rstd * gm.y + be.y;
  outv.z = (v.z - mean) * rstd * gm.z + be.z;
  outv.w = (v.w - mean) * rstd * gm.w + be.w;
  *reinterpret_cast<float4*>(&y[(size_t)row * EDIM + tid * 4]) = outv;
}

extern "C" void kernel_launch(void* const* d_in, const int* in_sizes, int n_in,
                              void* d_out, int out_size, void* d_ws,
                              size_t ws_size, hipStream_t stream) {
  const float* x = (const float*)d_in[0];
  const float* W_qkv = (const float*)d_in[1];
  const float* b_qkv = (const float*)d_in[2];
  const float* W_proj = (const float*)d_in[3];
  const float* b_proj = (const float*)d_in[4];
  const float* gamma = (const float*)d_in[5];
  const float* beta = (const float*)d_in[6];
  float* out = (float*)d_out;

  uint8_t* p = (uint8_t*)d_ws;
  unsigned short* x_bf = (unsigned short*)p;            p += (size_t)MROWS * EDIM * 2;      // 8 MB
  unsigned short* wqkv_bf = (unsigned short*)p;         p += (size_t)3 * EDIM * EDIM * 2;   // 6 MB
  unsigned short* wproj_bf = (unsigned short*)p;        p += (size_t)EDIM * EDIM * 2;       // 2 MB
  unsigned short* Qb = (unsigned short*)p;              p += (size_t)MROWS * EDIM * 2;      // 8 MB
  unsigned short* Kb = (unsigned short*)p;              p += (size_t)MROWS * EDIM * 2;      // 8 MB
  unsigned short* Vb = (unsigned short*)p;              p += (size_t)MROWS * EDIM * 2;      // 8 MB
  unsigned short* Vtb = (unsigned short*)p;             p += (size_t)MROWS * EDIM * 2;      // 8 MB
  unsigned short* AOb = (unsigned short*)p;             p += (size_t)MROWS * EDIM * 2;      // 8 MB

  // fp32 -> bf16 converts
  cvt_kernel<<<(MROWS * EDIM / 8 + 255) / 256, 256, 0, stream>>>(x, x_bf, MROWS * EDIM);
  cvt_kernel<<<(3 * EDIM * EDIM / 8 + 255) / 256, 256, 0, stream>>>(W_qkv, wqkv_bf, 3 * EDIM * EDIM);
  cvt_kernel<<<(EDIM * EDIM / 8 + 255) / 256, 256, 0, stream>>>(W_proj, wproj_bf, EDIM * EDIM);

  // QKV projection -> Q(*scale)/K/V bf16 [B,H,S,D]
  gemm_bf16<0><<<dim3(24, 32), 256, 0, stream>>>(x_bf, wqkv_bf, b_qkv, nullptr,
                                                 Qb, Kb, Vb, nullptr,
                                                 MROWS, 3 * EDIM, EDIM);
  // V -> V^T [B,H,D,S]
  vtrans_kernel<<<dim3(SEQ / 64, BATCH * NHEADS), 256, 0, stream>>>(Vb, Vtb);
  // flash attention -> AO bf16 [B,S,E]
  attn_mfma<<<dim3(SEQ / 128, BATCH * NHEADS), 256, 0, stream>>>(Qb, Kb, Vtb, AOb);
  // out projection + bias + residual -> fp32 y
  gemm_bf16<1><<<dim3(8, 32), 256, 0, stream>>>(AOb, wproj_bf, b_proj, x,
                                                nullptr, nullptr, nullptr, out,
                                                MROWS, EDIM, EDIM);
  // in-place LayerNorm
  ln_kernel<<<MROWS, 256, 0, stream>>>(out, gamma, beta);
}